// Round 8
// baseline (285.270 us; speedup 1.0000x reference)
//
#include <hip/hip_runtime.h>
#include <hip/hip_bf16.h>

#define NVOX 200000
#define NTAP 27
#define OSTR 68   // out LDS row stride (floats)
#define ROWB 128  // bytes per bf16 feature row (64 ch)
#define VPB  128  // voxels per block (tail block clamped)

typedef __bf16          bf16x8 __attribute__((ext_vector_type(8)));
typedef unsigned short  u16x8  __attribute__((ext_vector_type(8)));
typedef float           f32x4  __attribute__((ext_vector_type(4)));

// ws layout (bytes). fbuf/hbuf have NVOX+1 rows; row NVOX is the zero
// sentinel so gathers are branchless.
#define FB_BYTES    ((size_t)(NVOX + 1) * ROWB)      // 25,600,128
#define WSHUF_BYTES (NTAP * 2 * 4 * 64 * 16)         // 221,184 per conv
#define FB_OFF      0
#define H_OFF       (FB_BYTES)
#define WS1_OFF     (2 * FB_BYTES)
#define WS2_OFF     (WS1_OFF + WSHUF_BYTES)
#define FLAG_OFF    (WS2_OFF + WSHUF_BYTES)

static __device__ __forceinline__ unsigned short f2bf_bits(float f) {
    __hip_bfloat16 h = __float2bfloat16(f);
    union { __hip_bfloat16 h; unsigned short u; } u; u.h = h; return u.u;
}
static __device__ __forceinline__ float bf2f(unsigned short s) {
    union { float f; unsigned u; } u; u.u = ((unsigned)s) << 16; return u.f;
}
static __device__ __forceinline__ float ld_param(const void* p, int c, int isbf) {
    return isbf ? bf2f(((const unsigned short*)p)[c]) : ((const float*)p)[c];
}
// async DMA: 16 B from global (per-lane addr) -> LDS (wave-uniform base + lane*16)
static __device__ __forceinline__ void gload_lds16(const void* gp, void* lp) {
    __builtin_amdgcn_global_load_lds(
        (const __attribute__((address_space(1))) void*)gp,
        (__attribute__((address_space(3))) void*)lp, 16, 0, 0);
}
// wave-uniform: are float tensors packed bf16? (v1 in [0.5,1.5] -> 0x3F00..0x3FC0)
static __device__ __forceinline__ int wave_isbf(const unsigned* v1w) {
    int l = threadIdx.x & 63;
    int ok = 1;
    if (l < 32) {
        unsigned w = v1w[l], lo = w & 0xFFFFu, hi = w >> 16;
        ok = (lo >= 0x3F00u && lo <= 0x3FC0u && hi >= 0x3F00u && hi <= 0x3FC0u);
    }
    return __all(ok);
}

// -------- mega-prep: feats->bf16 fbuf (blocks 0..6249), W-shuffle
// (6250..6357), flags + sentinel-row zeroing (6358)  [unchanged, verified]
__global__ __launch_bounds__(256)
void prep_kernel(const void* __restrict__ feats,
                 const void* __restrict__ W1, const void* __restrict__ W2,
                 const unsigned* __restrict__ v1w, const unsigned* __restrict__ nbrw,
                 uint4* __restrict__ fbuf, uint4* __restrict__ hbuf,
                 uint4* __restrict__ Ws1, uint4* __restrict__ Ws2,
                 int* __restrict__ flags) {
    const int bx = blockIdx.x;
    if (bx < 6250) {
        const int isbf = wave_isbf(v1w);
        size_t t = (size_t)bx * 256 + threadIdx.x;   // fragment id (16 B)
        if (isbf) {
            fbuf[t] = ((const uint4*)feats)[t];
        } else {
            float4 a = ((const float4*)feats)[2 * t];
            float4 b = ((const float4*)feats)[2 * t + 1];
            union { uint4 q; unsigned short u[8]; } o;
            o.u[0] = f2bf_bits(a.x); o.u[1] = f2bf_bits(a.y);
            o.u[2] = f2bf_bits(a.z); o.u[3] = f2bf_bits(a.w);
            o.u[4] = f2bf_bits(b.x); o.u[5] = f2bf_bits(b.y);
            o.u[6] = f2bf_bits(b.z); o.u[7] = f2bf_bits(b.w);
            fbuf[t] = o.q;
        }
    } else if (bx < 6358) {
        const int isbf = wave_isbf(v1w);
        int t = (bx - 6250) * 256 + threadIdx.x;     // < 27648
        const void* W = (t < 13824) ? W1 : W2;
        uint4* Ws     = (t < 13824) ? Ws1 : Ws2;
        int f = (t < 13824) ? t : t - 13824;
        int k  = f / 512;
        int r  = f % 512;
        int kc = r / 256;
        int r2 = r % 256;
        int nc = r2 / 64;
        int l  = r2 % 64;
        int quad = l >> 4, li = l & 15;
        unsigned short tmp[8];
#pragma unroll
        for (int j = 0; j < 8; ++j) {
            int off = k * 4096 + (kc * 32 + quad * 8 + j) * 64 + (nc * 16 + li);
            tmp[j] = isbf ? ((const unsigned short*)W)[off]
                          : f2bf_bits(((const float*)W)[off]);
        }
        uint4 v;
        v.x = (unsigned)tmp[0] | ((unsigned)tmp[1] << 16);
        v.y = (unsigned)tmp[2] | ((unsigned)tmp[3] << 16);
        v.z = (unsigned)tmp[4] | ((unsigned)tmp[5] << 16);
        v.w = (unsigned)tmp[6] | ((unsigned)tmp[7] << 16);
        Ws[f] = v;
    } else {
        int t = threadIdx.x;
        if (t < 64) {
            int isbf = wave_isbf(v1w);
            int n64ok = 1;
#pragma unroll
            for (int i = 0; i < 8; ++i)   // int64 nbr: every odd dword zero
                if (nbrw[2 * (t * 8 + i) + 1] != 0u) n64ok = 0;
            int n64 = __all(n64ok);
            if (t == 0) { flags[0] = isbf; flags[1] = n64; }
        }
        uint4 z = make_uint4(0u, 0u, 0u, 0u);
        if (t >= 64 && t < 72) fbuf[(size_t)NVOX * 8 + (t - 64)] = z;
        if (t >= 72 && t < 80) hbuf[(size_t)NVOX * 8 + (t - 72)] = z;
    }
}

// async-stage tap kk's rows for THIS wave's 4 DMA slot-sets (rows
// [32w, 32w+32)), each 8-row slot gated by its 16-row group's mask bit
// (wave-uniform). nbr indices from global (8-lane broadcast, L1-hot);
// tail-block rows >= NVOX forced to sentinel via badN. XOR swizzle: slot s
// holds logical frag f=(s - s/8)&7 of row s/8 via the gathered address.
#define STG(kk, bp) do {                                                    \
    if ((mga >> (kk)) & 1) {                                                \
        int ia_ = bad0 ? NVOX : nbrG[o0 + (kk) * tmul];                     \
        int ib_ = bad1 ? NVOX : nbrG[o1 + (kk) * tmul];                     \
        gload_lds16(srcB + (size_t)ia_ * ROWB + f0 * 16,                    \
                    (void*)((bp) + w * 256));                               \
        gload_lds16(srcB + (size_t)ib_ * ROWB + f1 * 16,                    \
                    (void*)((bp) + w * 256 + 64));                          \
    }                                                                       \
    if ((mgb >> (kk)) & 1) {                                                \
        int ic_ = bad2 ? NVOX : nbrG[o2 + (kk) * tmul];                     \
        int id_ = bad3 ? NVOX : nbrG[o3 + (kk) * tmul];                     \
        gload_lds16(srcB + (size_t)ic_ * ROWB + f2 * 16,                    \
                    (void*)((bp) + w * 256 + 128));                         \
        gload_lds16(srcB + (size_t)id_ * ROWB + f3 * 16,                    \
                    (void*)((bp) + w * 256 + 192));                         \
    } } while (0)

#define LOADB(kk, B0r, B1r) do {                                            \
    B0r = Ws[(kk) * 512 + w * 64 + l];                                      \
    B1r = Ws[(kk) * 512 + 256 + w * 64 + l];                                \
} while (0)

// MFMAs of tap kk from LDS tile bp: 8 row-groups, group-gated
#define COMPUTE(kk, bp, B0, B1) do {                                        \
    _Pragma("unroll")                                                       \
    for (int g = 0; g < 8; ++g) {                                           \
        if ((mg[g] >> (kk)) & 1) {                                          \
            bf16x8 a0_ = *(const bf16x8*)((bp) + ro0[g]);                   \
            bf16x8 a1_ = *(const bf16x8*)((bp) + ro1[g]);                   \
            acc[g] = __builtin_amdgcn_mfma_f32_16x16x32_bf16(a0_, B0, acc[g], 0, 0, 0); \
            acc[g] = __builtin_amdgcn_mfma_f32_16x16x32_bf16(a1_, B1, acc[g], 0, 0, 0); \
        }                                                                   \
    }                                                                       \
} while (0)

// -------- fused sparse-conv + BN (+ residual) + ReLU
// R8: R7 measured dur INDEPENDENT of waves (R0 45% occ / R7 62% occ, both
// 66us) -> shared-throughput bound. Estimated L2 traffic 1.06 GB/conv
// (B 691 MB = Ws re-read per 64-vox block!) at 16 TB/s = the whole 66us.
// Fix: VPB 64 -> 128 halves B traffic (345 MB); A unchanged. Same 4-wave
// round structure; wave w owns cout chunk w across 8 row-groups (acc[8]);
// stages 4 gated 8-row DMA slots. LDS 34.8 KB -> 4 blocks/CU.
__global__ __launch_bounds__(256, 4)
void conv_bn_kernel(const uint4* __restrict__ srcV,   // (NVOX+1) x 8 uint4 bf16 rows
                    const void* __restrict__ nbr,
                    const bf16x8* __restrict__ Ws,
                    const void* __restrict__ gg, const void* __restrict__ bb,
                    const void* __restrict__ mm, const void* __restrict__ vv,
                    const u16x8* __restrict__ resid,  // bf16 fbuf rows, null for conv1
                    const int* __restrict__ flags,
                    void* __restrict__ dst, int final_out) {
    // smi: mask[8] | A-tiles 2x1024 uint4 at int-ofs 8 (byte 32, 16B-
    // aligned). Epilogue outLDS (128x68 f32 = 34816 B) aliases smi.
    __shared__ __align__(16) int smi[VPB * OSTR];
    int*   maskLDS = smi;
    uint4* at0     = (uint4*)(smi + 8);
    uint4* at1     = at0 + 1024;
    float* outLDS  = (float*)smi;

    const int tid  = threadIdx.x;
    // bijective XCD-aware swizzle (verified: FETCH 46->26-40 MB)
    const int nwg  = gridDim.x;
    const int orig = blockIdx.x;
    const int qq   = nwg >> 3, rr = nwg & 7;
    const int xcd  = orig & 7, idx = orig >> 3;
    const int bid  = (xcd < rr ? xcd * (qq + 1) : rr * (qq + 1) + (xcd - rr) * qq) + idx;
    const int base = bid * VPB;

    const int isbf = flags[0];
    const int n64  = flags[1];
    const char* srcB = (const char*)srcV;

    // nbr as int32 view: element (v*27+k) lives at int32 slot v*smul+k*tmul
    const int* nbrG = (const int*)nbr;
    const int  tmul = n64 ? 2 : 1;
    const int  smul = NTAP * tmul;

    if (tid < 8) maskLDS[tid] = 0;
    __syncthreads();

    // per-(tap, 16-voxel-group) validity bitmask — 8 groups, tail-safe
    if (tid < NTAP * 8) {
        int k = tid >> 3, g = tid & 7;
        int mn = 0x7fffffff;
#pragma unroll
        for (int r = 0; r < 16; ++r) {
            int vx = base + g * 16 + r;
            int safe = vx < NVOX ? vx : NVOX - 1;
            int v = nbrG[safe * smul + k * tmul];
            if (vx >= NVOX) v = NVOX;
            mn = min(mn, v);
        }
        if (mn < NVOX) atomicOr(&maskLDS[g], 1 << k);
    }
    __syncthreads();

    const int w = tid >> 6, l = tid & 63;
    const int quad = l >> 4, li = l & 15;

    int mg[8];
#pragma unroll
    for (int g = 0; g < 8; ++g) mg[g] = __builtin_amdgcn_readfirstlane(maskLDS[g]);
    const int mga = __builtin_amdgcn_readfirstlane(maskLDS[2 * w]);      // rows [32w,32w+16)
    const int mgb = __builtin_amdgcn_readfirstlane(maskLDS[2 * w + 1]);  // rows [32w+16,32w+32)

    // staging geometry: wave w's 4 DMA slot-sets cover rows [32w, 32w+32)
    // slot s = w*256 + j*64 + l; row = s>>3; frag f = (s - s>>3) & 7
    int o_[4], f_[4], bad_[4];
#pragma unroll
    for (int j = 0; j < 4; ++j) {
        int s  = w * 256 + j * 64 + l;
        int r  = s >> 3;
        f_[j]  = (s - r) & 7;
        int vx = base + r;
        bad_[j] = vx >= NVOX;
        o_[j]  = (bad_[j] ? NVOX - 1 : vx) * smul;
    }
    const int o0 = o_[0], o1 = o_[1], o2 = o_[2], o3 = o_[3];
    const int f0 = f_[0], f1 = f_[1], f2 = f_[2], f3 = f_[3];
    const int bad0 = bad_[0], bad1 = bad_[1], bad2 = bad_[2], bad3 = bad_[3];

    // compute-side fragment read offsets (uint4 units, constant across taps)
    int ro0[8], ro1[8];
#pragma unroll
    for (int g = 0; g < 8; ++g) {
        int row = g * 16 + li;
        ro0[g] = row * 8 + ((quad + row) & 7);
        ro1[g] = row * 8 + ((quad + 4 + row) & 7);
    }

    f32x4 acc[8];
#pragma unroll
    for (int g = 0; g < 8; ++g) acc[g] = (f32x4){0.f, 0.f, 0.f, 0.f};

    bf16x8 xB0, xB1, yB0, yB1;

    // prologue: tap 0 -> at0
    STG(0, at0);
    LOADB(0, xB0, xB1);
    __syncthreads();   // drains DMA -> at0 (tap 0) ready

    for (int k = 0; k < 26; k += 2) {
        STG(k + 1, at1);
        LOADB(k + 1, yB0, yB1);
        COMPUTE(k, at0, xB0, xB1);
        __syncthreads();   // drains -> at1 (tap k+1) ready
        STG(k + 2, at0);   // k+2 <= 26
        LOADB(k + 2, xB0, xB1);
        COMPUTE(k + 1, at1, yB0, yB1);
        __syncthreads();   // drains -> at0 (tap k+2) ready
    }
    COMPUTE(26, at0, xB0, xB1);

    // BN into LDS tile (pre-activation), then coalesced writeout
    const int c = w * 16 + li;
    float scale = ld_param(gg, c, isbf) * rsqrtf(ld_param(vv, c, isbf) + 1e-5f);
    float offs  = ld_param(bb, c, isbf) - ld_param(mm, c, isbf) * scale;

    __syncthreads();   // all waves done with tiles/masks (outLDS aliases them)
#pragma unroll
    for (int g = 0; g < 8; ++g)
#pragma unroll
        for (int r = 0; r < 4; ++r)
            outLDS[(g * 16 + quad * 4 + r) * OSTR + c] = acc[g][r] * scale + offs;
    __syncthreads();

    // thread t -> rows {t>>2, 64+t>>2}, 16-channel chunk t&3 (32 B/lane)
#pragma unroll
    for (int half = 0; half < 2; ++half) {
        int trow = half * 64 + (tid >> 2), cc = tid & 3;
        long grow = base + trow;
        if (grow < NVOX) {
            const float4* lp = (const float4*)&outLDS[trow * OSTR + cc * 16];
            float4 q0 = lp[0], q1 = lp[1], q2 = lp[2], q3 = lp[3];
            float vals[16] = {q0.x, q0.y, q0.z, q0.w, q1.x, q1.y, q1.z, q1.w,
                              q2.x, q2.y, q2.z, q2.w, q3.x, q3.y, q3.z, q3.w};

            if (resid) {
                const u16x8* rp = resid + grow * 8 + cc * 2;
                u16x8 r0v = rp[0], r1v = rp[1];
#pragma unroll
                for (int j = 0; j < 8; ++j) { vals[j] += bf2f(r0v[j]); vals[8 + j] += bf2f(r1v[j]); }
            }
#pragma unroll
            for (int j = 0; j < 16; ++j) vals[j] = fmaxf(vals[j], 0.f);

            const int store_bf = (!final_out) || isbf;
            if (store_bf) {
                u16x8 o0v, o1v;
#pragma unroll
                for (int j = 0; j < 8; ++j) { o0v[j] = f2bf_bits(vals[j]); o1v[j] = f2bf_bits(vals[8 + j]); }
                u16x8* dp = (u16x8*)dst + grow * 8 + cc * 2;
                dp[0] = o0v; dp[1] = o1v;
            } else {
                float4* dp = (float4*)dst + grow * 16 + cc * 4;
                dp[0] = (float4){vals[0], vals[1], vals[2], vals[3]};
                dp[1] = (float4){vals[4], vals[5], vals[6], vals[7]};
                dp[2] = (float4){vals[8], vals[9], vals[10], vals[11]};
                dp[3] = (float4){vals[12], vals[13], vals[14], vals[15]};
            }
        }
    }
}

extern "C" void kernel_launch(void* const* d_in, const int* in_sizes, int n_in,
                              void* d_out, int out_size, void* d_ws, size_t ws_size,
                              hipStream_t stream) {
    const void* feats = d_in[0];
    const void* nbr   = d_in[1];
    const void* W1    = d_in[2];
    const void* g1    = d_in[3];
    const void* b1    = d_in[4];
    const void* m1    = d_in[5];
    const void* v1    = d_in[6];
    const void* W2    = d_in[7];
    const void* g2    = d_in[8];
    const void* b2    = d_in[9];
    const void* m2    = d_in[10];
    const void* v2    = d_in[11];

    char* ws = (char*)d_ws;
    uint4* fbuf = (uint4*)(ws + FB_OFF);
    uint4* hbuf = (uint4*)(ws + H_OFF);
    uint4* Ws1  = (uint4*)(ws + WS1_OFF);
    uint4* Ws2  = (uint4*)(ws + WS2_OFF);
    int*   flags = (int*)(ws + FLAG_OFF);

    prep_kernel<<<dim3(6359), dim3(256), 0, stream>>>(
        feats, W1, W2, (const unsigned*)v1, (const unsigned*)nbr,
        fbuf, hbuf, Ws1, Ws2, flags);

    const int nblk = (NVOX + VPB - 1) / VPB;   // 1563 (tail clamped)
    conv_bn_kernel<<<dim3(nblk), dim3(256), 0, stream>>>(
        fbuf, nbr, (const bf16x8*)Ws1, g1, b1, m1, v1,
        /*resid=*/nullptr, flags, hbuf, /*final_out=*/0);

    conv_bn_kernel<<<dim3(nblk), dim3(256), 0, stream>>>(
        hbuf, nbr, (const bf16x8*)Ws2, g2, b2, m2, v2,
        /*resid=*/(const u16x8*)fbuf, flags, d_out, /*final_out=*/1);
}

// Round 9
// 283.237 us; speedup vs baseline: 1.0072x; 1.0072x over previous
//
#include <hip/hip_runtime.h>
#include <hip/hip_bf16.h>

#define NVOX 200000
#define NTAP 27
#define OSTR 68   // out LDS row stride (floats)
#define ROWB 128  // bytes per bf16 feature row (64 ch)
#define VPB  96   // voxels per block (multiple of 32; tail block clamped)

typedef __bf16          bf16x8 __attribute__((ext_vector_type(8)));
typedef unsigned short  u16x8  __attribute__((ext_vector_type(8)));
typedef float           f32x4  __attribute__((ext_vector_type(4)));

// ws layout (bytes). fbuf/hbuf have NVOX+1 rows; row NVOX is the zero
// sentinel so gathers are branchless.
#define FB_BYTES    ((size_t)(NVOX + 1) * ROWB)      // 25,600,128
#define WSHUF_BYTES (NTAP * 2 * 4 * 64 * 16)         // 221,184 per conv
#define FB_OFF      0
#define H_OFF       (FB_BYTES)
#define WS1_OFF     (2 * FB_BYTES)
#define WS2_OFF     (WS1_OFF + WSHUF_BYTES)
#define FLAG_OFF    (WS2_OFF + WSHUF_BYTES)

static __device__ __forceinline__ unsigned short f2bf_bits(float f) {
    __hip_bfloat16 h = __float2bfloat16(f);
    union { __hip_bfloat16 h; unsigned short u; } u; u.h = h; return u.u;
}
static __device__ __forceinline__ float bf2f(unsigned short s) {
    union { float f; unsigned u; } u; u.u = ((unsigned)s) << 16; return u.f;
}
static __device__ __forceinline__ float ld_param(const void* p, int c, int isbf) {
    return isbf ? bf2f(((const unsigned short*)p)[c]) : ((const float*)p)[c];
}
// async DMA: 16 B from global (per-lane addr) -> LDS (wave-uniform base + lane*16)
static __device__ __forceinline__ void gload_lds16(const void* gp, void* lp) {
    __builtin_amdgcn_global_load_lds(
        (const __attribute__((address_space(1))) void*)gp,
        (__attribute__((address_space(3))) void*)lp, 16, 0, 0);
}
// wave-uniform: are float tensors packed bf16? (v1 in [0.5,1.5] -> 0x3F00..0x3FC0)
static __device__ __forceinline__ int wave_isbf(const unsigned* v1w) {
    int l = threadIdx.x & 63;
    int ok = 1;
    if (l < 32) {
        unsigned w = v1w[l], lo = w & 0xFFFFu, hi = w >> 16;
        ok = (lo >= 0x3F00u && lo <= 0x3FC0u && hi >= 0x3F00u && hi <= 0x3FC0u);
    }
    return __all(ok);
}

// -------- mega-prep: feats->bf16 fbuf (blocks 0..6249), W-shuffle
// (6250..6357), flags + sentinel-row zeroing (6358)  [unchanged, verified]
__global__ __launch_bounds__(256)
void prep_kernel(const void* __restrict__ feats,
                 const void* __restrict__ W1, const void* __restrict__ W2,
                 const unsigned* __restrict__ v1w, const unsigned* __restrict__ nbrw,
                 uint4* __restrict__ fbuf, uint4* __restrict__ hbuf,
                 uint4* __restrict__ Ws1, uint4* __restrict__ Ws2,
                 int* __restrict__ flags) {
    const int bx = blockIdx.x;
    if (bx < 6250) {
        const int isbf = wave_isbf(v1w);
        size_t t = (size_t)bx * 256 + threadIdx.x;   // fragment id (16 B)
        if (isbf) {
            fbuf[t] = ((const uint4*)feats)[t];
        } else {
            float4 a = ((const float4*)feats)[2 * t];
            float4 b = ((const float4*)feats)[2 * t + 1];
            union { uint4 q; unsigned short u[8]; } o;
            o.u[0] = f2bf_bits(a.x); o.u[1] = f2bf_bits(a.y);
            o.u[2] = f2bf_bits(a.z); o.u[3] = f2bf_bits(a.w);
            o.u[4] = f2bf_bits(b.x); o.u[5] = f2bf_bits(b.y);
            o.u[6] = f2bf_bits(b.z); o.u[7] = f2bf_bits(b.w);
            fbuf[t] = o.q;
        }
    } else if (bx < 6358) {
        const int isbf = wave_isbf(v1w);
        int t = (bx - 6250) * 256 + threadIdx.x;     // < 27648
        const void* W = (t < 13824) ? W1 : W2;
        uint4* Ws     = (t < 13824) ? Ws1 : Ws2;
        int f = (t < 13824) ? t : t - 13824;
        int k  = f / 512;
        int r  = f % 512;
        int kc = r / 256;
        int r2 = r % 256;
        int nc = r2 / 64;
        int l  = r2 % 64;
        int quad = l >> 4, li = l & 15;
        unsigned short tmp[8];
#pragma unroll
        for (int j = 0; j < 8; ++j) {
            int off = k * 4096 + (kc * 32 + quad * 8 + j) * 64 + (nc * 16 + li);
            tmp[j] = isbf ? ((const unsigned short*)W)[off]
                          : f2bf_bits(((const float*)W)[off]);
        }
        uint4 v;
        v.x = (unsigned)tmp[0] | ((unsigned)tmp[1] << 16);
        v.y = (unsigned)tmp[2] | ((unsigned)tmp[3] << 16);
        v.z = (unsigned)tmp[4] | ((unsigned)tmp[5] << 16);
        v.w = (unsigned)tmp[6] | ((unsigned)tmp[7] << 16);
        Ws[f] = v;
    } else {
        int t = threadIdx.x;
        if (t < 64) {
            int isbf = wave_isbf(v1w);
            int n64ok = 1;
#pragma unroll
            for (int i = 0; i < 8; ++i)   // int64 nbr: every odd dword zero
                if (nbrw[2 * (t * 8 + i) + 1] != 0u) n64ok = 0;
            int n64 = __all(n64ok);
            if (t == 0) { flags[0] = isbf; flags[1] = n64; }
        }
        uint4 z = make_uint4(0u, 0u, 0u, 0u);
        if (t >= 64 && t < 72) fbuf[(size_t)NVOX * 8 + (t - 64)] = z;
        if (t >= 72 && t < 80) hbuf[(size_t)NVOX * 8 + (t - 72)] = z;
    }
}

// async-stage tap kk's rows for THIS wave's 3 DMA slots (rows [24w,24w+24)),
// each 8-row slot gated by its 16-row group's mask bit (group (24w+8j)>>4
// is wave-uniform per slot). nbr indices from global (8-lane broadcast,
// L1-hot); tail rows forced to sentinel via badN. XOR swizzle: slot s holds
// logical frag f=(s - s/8)&7 of row s/8 via the gathered address.
#define STG(kk, bp) do {                                                    \
    if ((gm0 >> (kk)) & 1) {                                                \
        int ia_ = bad0 ? NVOX : nbrG[o0 + (kk) * tmul];                     \
        gload_lds16(srcB + (size_t)ia_ * ROWB + f0 * 16,                    \
                    (void*)((bp) + w * 192));                               \
    }                                                                       \
    if ((gm1 >> (kk)) & 1) {                                                \
        int ib_ = bad1 ? NVOX : nbrG[o1 + (kk) * tmul];                     \
        gload_lds16(srcB + (size_t)ib_ * ROWB + f1 * 16,                    \
                    (void*)((bp) + w * 192 + 64));                          \
    }                                                                       \
    if ((gm2 >> (kk)) & 1) {                                                \
        int ic_ = bad2 ? NVOX : nbrG[o2 + (kk) * tmul];                     \
        gload_lds16(srcB + (size_t)ic_ * ROWB + f2 * 16,                    \
                    (void*)((bp) + w * 192 + 128));                         \
    } } while (0)

#define LOADB(kk, B0r, B1r) do {                                            \
    B0r = Ws[(kk) * 512 + w * 64 + l];                                      \
    B1r = Ws[(kk) * 512 + 256 + w * 64 + l];                                \
} while (0)

// MFMAs of tap kk from LDS tile bp: 6 row-groups, group-gated
#define COMPUTE(kk, bp, B0, B1) do {                                        \
    _Pragma("unroll")                                                       \
    for (int g = 0; g < 6; ++g) {                                           \
        if ((mg[g] >> (kk)) & 1) {                                          \
            bf16x8 a0_ = *(const bf16x8*)((bp) + ro0[g]);                   \
            bf16x8 a1_ = *(const bf16x8*)((bp) + ro1[g]);                   \
            acc[g] = __builtin_amdgcn_mfma_f32_16x16x32_bf16(a0_, B0, acc[g], 0, 0, 0); \
            acc[g] = __builtin_amdgcn_mfma_f32_16x16x32_bf16(a1_, B1, acc[g], 0, 0, 0); \
        }                                                                   \
    }                                                                       \
} while (0)

// -------- fused sparse-conv + BN (+ residual) + ReLU
// R9: dur = max(C(VPB)/waves, L2-floor(VPB)). R8 proved bigger tiles cut C
// (873 vs 940 wave-us) but 34.8KB LDS -> 30% occ -> latency-bound at 90us.
// VPB=96 is the largest multiple-of-32 tile that keeps 6 blocks/CU:
// LDS = out-tile 96x68x4 = 26.1KB (A-tiles 24.6KB alias under it) -> 24
// waves static (75%). B traffic 675->450 MB; 2084 blocks (8.1/CU balance).
__global__ __launch_bounds__(256, 6)
void conv_bn_kernel(const uint4* __restrict__ srcV,   // (NVOX+1) x 8 uint4 bf16 rows
                    const void* __restrict__ nbr,
                    const bf16x8* __restrict__ Ws,
                    const void* __restrict__ gg, const void* __restrict__ bb,
                    const void* __restrict__ mm, const void* __restrict__ vv,
                    const u16x8* __restrict__ resid,  // bf16 fbuf rows, null for conv1
                    const int* __restrict__ flags,
                    void* __restrict__ dst, int final_out) {
    // smi: mask[6]+pad at 0..7 | A-tiles 2x768 uint4 at int-ofs 8 (byte 32,
    // 16B-aligned, ends at int 6152). Epilogue outLDS (96x68 = 6528 ints)
    // aliases the whole region. LDS = 26,112 B -> 6 blocks/CU.
    __shared__ __align__(16) int smi[VPB * OSTR];
    int*   maskLDS = smi;
    uint4* at0     = (uint4*)(smi + 8);
    uint4* at1     = at0 + 768;
    float* outLDS  = (float*)smi;

    const int tid  = threadIdx.x;
    // bijective XCD-aware swizzle (verified: FETCH 46->26-40 MB)
    const int nwg  = gridDim.x;
    const int orig = blockIdx.x;
    const int qq   = nwg >> 3, rr = nwg & 7;
    const int xcd  = orig & 7, idx = orig >> 3;
    const int bid  = (xcd < rr ? xcd * (qq + 1) : rr * (qq + 1) + (xcd - rr) * qq) + idx;
    const int base = bid * VPB;

    const int isbf = flags[0];
    const int n64  = flags[1];
    const char* srcB = (const char*)srcV;

    // nbr as int32 view: element (v*27+k) lives at int32 slot v*smul+k*tmul
    const int* nbrG = (const int*)nbr;
    const int  tmul = n64 ? 2 : 1;
    const int  smul = NTAP * tmul;

    if (tid < 6) maskLDS[tid] = 0;
    __syncthreads();

    // per-(tap, 16-voxel-group) validity bitmask — 6 groups, tail-safe
    if (tid < NTAP * 6) {
        int k = tid / 6, g = tid % 6;
        int mn = 0x7fffffff;
#pragma unroll
        for (int r = 0; r < 16; ++r) {
            int vx = base + g * 16 + r;
            int safe = vx < NVOX ? vx : NVOX - 1;
            int v = nbrG[safe * smul + k * tmul];
            if (vx >= NVOX) v = NVOX;
            mn = min(mn, v);
        }
        if (mn < NVOX) atomicOr(&maskLDS[g], 1 << k);
    }
    __syncthreads();

    const int w = tid >> 6, l = tid & 63;
    const int quad = l >> 4, li = l & 15;

    int mg[6];
#pragma unroll
    for (int g = 0; g < 6; ++g) mg[g] = __builtin_amdgcn_readfirstlane(maskLDS[g]);
    // per-slot staging gates: slot j of wave w covers rows [24w+8j, +8),
    // all inside group (24w+8j)>>4 (wave-uniform)
    const int gm0 = mg[(24 * w + 0)  >> 4];
    const int gm1 = mg[(24 * w + 8)  >> 4];
    const int gm2 = mg[(24 * w + 16) >> 4];

    // staging geometry: wave w's 3 DMA slots cover rows [24w, 24w+24)
    // slot s = w*192 + j*64 + l; row = s>>3; frag f = (s - s>>3) & 7
    int o_[3], f_[3], bad_[3];
#pragma unroll
    for (int j = 0; j < 3; ++j) {
        int s  = w * 192 + j * 64 + l;
        int r  = s >> 3;
        f_[j]  = (s - r) & 7;
        int vx = base + r;
        bad_[j] = vx >= NVOX;
        o_[j]  = (bad_[j] ? NVOX - 1 : vx) * smul;
    }
    const int o0 = o_[0], o1 = o_[1], o2 = o_[2];
    const int f0 = f_[0], f1 = f_[1], f2 = f_[2];
    const int bad0 = bad_[0], bad1 = bad_[1], bad2 = bad_[2];

    // compute-side fragment read offsets (uint4 units, constant across taps)
    int ro0[6], ro1[6];
#pragma unroll
    for (int g = 0; g < 6; ++g) {
        int row = g * 16 + li;
        ro0[g] = row * 8 + ((quad + row) & 7);
        ro1[g] = row * 8 + ((quad + 4 + row) & 7);
    }

    f32x4 acc[6];
#pragma unroll
    for (int g = 0; g < 6; ++g) acc[g] = (f32x4){0.f, 0.f, 0.f, 0.f};

    bf16x8 xB0, xB1, yB0, yB1;

    // prologue: tap 0 -> at0
    STG(0, at0);
    LOADB(0, xB0, xB1);
    __syncthreads();   // drains DMA -> at0 (tap 0) ready

    for (int k = 0; k < 26; k += 2) {
        STG(k + 1, at1);
        LOADB(k + 1, yB0, yB1);
        COMPUTE(k, at0, xB0, xB1);
        __syncthreads();   // drains -> at1 (tap k+1) ready
        STG(k + 2, at0);   // k+2 <= 26
        LOADB(k + 2, xB0, xB1);
        COMPUTE(k + 1, at1, yB0, yB1);
        __syncthreads();   // drains -> at0 (tap k+2) ready
    }
    COMPUTE(26, at0, xB0, xB1);

    // BN into LDS tile (pre-activation), then coalesced writeout
    const int c = w * 16 + li;
    float scale = ld_param(gg, c, isbf) * rsqrtf(ld_param(vv, c, isbf) + 1e-5f);
    float offs  = ld_param(bb, c, isbf) - ld_param(mm, c, isbf) * scale;

    __syncthreads();   // all waves done with tiles/masks (outLDS aliases them)
#pragma unroll
    for (int g = 0; g < 6; ++g)
#pragma unroll
        for (int r = 0; r < 4; ++r)
            outLDS[(g * 16 + quad * 4 + r) * OSTR + c] = acc[g][r] * scale + offs;
    __syncthreads();

    // thread t -> rows {t>>2, 64+t>>2}, 16-channel chunk t&3 (32 B/lane)
#pragma unroll
    for (int half = 0; half < 2; ++half) {
        int trow = half * 64 + (tid >> 2), cc = tid & 3;
        long grow = base + trow;
        if (trow < VPB && grow < NVOX) {
            const float4* lp = (const float4*)&outLDS[trow * OSTR + cc * 16];
            float4 q0 = lp[0], q1 = lp[1], q2 = lp[2], q3 = lp[3];
            float vals[16] = {q0.x, q0.y, q0.z, q0.w, q1.x, q1.y, q1.z, q1.w,
                              q2.x, q2.y, q2.z, q2.w, q3.x, q3.y, q3.z, q3.w};

            if (resid) {
                const u16x8* rp = resid + grow * 8 + cc * 2;
                u16x8 r0v = rp[0], r1v = rp[1];
#pragma unroll
                for (int j = 0; j < 8; ++j) { vals[j] += bf2f(r0v[j]); vals[8 + j] += bf2f(r1v[j]); }
            }
#pragma unroll
            for (int j = 0; j < 16; ++j) vals[j] = fmaxf(vals[j], 0.f);

            const int store_bf = (!final_out) || isbf;
            if (store_bf) {
                u16x8 o0v, o1v;
#pragma unroll
                for (int j = 0; j < 8; ++j) { o0v[j] = f2bf_bits(vals[j]); o1v[j] = f2bf_bits(vals[8 + j]); }
                u16x8* dp = (u16x8*)dst + grow * 8 + cc * 2;
                dp[0] = o0v; dp[1] = o1v;
            } else {
                float4* dp = (float4*)dst + grow * 16 + cc * 4;
                dp[0] = (float4){vals[0], vals[1], vals[2], vals[3]};
                dp[1] = (float4){vals[4], vals[5], vals[6], vals[7]};
                dp[2] = (float4){vals[8], vals[9], vals[10], vals[11]};
                dp[3] = (float4){vals[12], vals[13], vals[14], vals[15]};
            }
        }
    }
}

extern "C" void kernel_launch(void* const* d_in, const int* in_sizes, int n_in,
                              void* d_out, int out_size, void* d_ws, size_t ws_size,
                              hipStream_t stream) {
    const void* feats = d_in[0];
    const void* nbr   = d_in[1];
    const void* W1    = d_in[2];
    const void* g1    = d_in[3];
    const void* b1    = d_in[4];
    const void* m1    = d_in[5];
    const void* v1    = d_in[6];
    const void* W2    = d_in[7];
    const void* g2    = d_in[8];
    const void* b2    = d_in[9];
    const void* m2    = d_in[10];
    const void* v2    = d_in[11];

    char* ws = (char*)d_ws;
    uint4* fbuf = (uint4*)(ws + FB_OFF);
    uint4* hbuf = (uint4*)(ws + H_OFF);
    uint4* Ws1  = (uint4*)(ws + WS1_OFF);
    uint4* Ws2  = (uint4*)(ws + WS2_OFF);
    int*   flags = (int*)(ws + FLAG_OFF);

    prep_kernel<<<dim3(6359), dim3(256), 0, stream>>>(
        feats, W1, W2, (const unsigned*)v1, (const unsigned*)nbr,
        fbuf, hbuf, Ws1, Ws2, flags);

    const int nblk = (NVOX + VPB - 1) / VPB;   // 2084 (tail clamped)
    conv_bn_kernel<<<dim3(nblk), dim3(256), 0, stream>>>(
        fbuf, nbr, (const bf16x8*)Ws1, g1, b1, m1, v1,
        /*resid=*/nullptr, flags, hbuf, /*final_out=*/0);

    conv_bn_kernel<<<dim3(nblk), dim3(256), 0, stream>>>(
        hbuf, nbr, (const bf16x8*)Ws2, g2, b2, m2, v2,
        /*resid=*/(const u16x8*)fbuf, flags, d_out, /*final_out=*/1);
}

// Round 10
// 265.716 us; speedup vs baseline: 1.0736x; 1.0659x over previous
//
#include <hip/hip_runtime.h>
#include <hip/hip_bf16.h>

#define NVOX 200000
#define NTAP 27
#define OSTR 68   // out LDS row stride (floats)
#define ROWB 128  // bytes per bf16 feature row (64 ch)
#define VPB  128  // voxels per block = 2 half-tiles of 64 (tail clamped)

typedef __bf16          bf16x8 __attribute__((ext_vector_type(8)));
typedef unsigned short  u16x8  __attribute__((ext_vector_type(8)));
typedef float           f32x4  __attribute__((ext_vector_type(4)));

// ws layout (bytes). fbuf/hbuf have NVOX+1 rows; row NVOX is the zero
// sentinel so gathers are branchless.
#define FB_BYTES    ((size_t)(NVOX + 1) * ROWB)      // 25,600,128
#define WSHUF_BYTES (NTAP * 2 * 4 * 64 * 16)         // 221,184 per conv
#define FB_OFF      0
#define H_OFF       (FB_BYTES)
#define WS1_OFF     (2 * FB_BYTES)
#define WS2_OFF     (WS1_OFF + WSHUF_BYTES)
#define FLAG_OFF    (WS2_OFF + WSHUF_BYTES)

static __device__ __forceinline__ unsigned short f2bf_bits(float f) {
    __hip_bfloat16 h = __float2bfloat16(f);
    union { __hip_bfloat16 h; unsigned short u; } u; u.h = h; return u.u;
}
static __device__ __forceinline__ float bf2f(unsigned short s) {
    union { float f; unsigned u; } u; u.u = ((unsigned)s) << 16; return u.f;
}
static __device__ __forceinline__ float ld_param(const void* p, int c, int isbf) {
    return isbf ? bf2f(((const unsigned short*)p)[c]) : ((const float*)p)[c];
}
// async DMA: 16 B from global (per-lane addr) -> LDS (wave-uniform base + lane*16)
static __device__ __forceinline__ void gload_lds16(const void* gp, void* lp) {
    __builtin_amdgcn_global_load_lds(
        (const __attribute__((address_space(1))) void*)gp,
        (__attribute__((address_space(3))) void*)lp, 16, 0, 0);
}
// wave-uniform: are float tensors packed bf16? (v1 in [0.5,1.5] -> 0x3F00..0x3FC0)
static __device__ __forceinline__ int wave_isbf(const unsigned* v1w) {
    int l = threadIdx.x & 63;
    int ok = 1;
    if (l < 32) {
        unsigned w = v1w[l], lo = w & 0xFFFFu, hi = w >> 16;
        ok = (lo >= 0x3F00u && lo <= 0x3FC0u && hi >= 0x3F00u && hi <= 0x3FC0u);
    }
    return __all(ok);
}

// -------- mega-prep: feats->bf16 fbuf (blocks 0..6249), W-shuffle
// (6250..6357), flags + sentinel-row zeroing (6358)  [unchanged, verified]
__global__ __launch_bounds__(256)
void prep_kernel(const void* __restrict__ feats,
                 const void* __restrict__ W1, const void* __restrict__ W2,
                 const unsigned* __restrict__ v1w, const unsigned* __restrict__ nbrw,
                 uint4* __restrict__ fbuf, uint4* __restrict__ hbuf,
                 uint4* __restrict__ Ws1, uint4* __restrict__ Ws2,
                 int* __restrict__ flags) {
    const int bx = blockIdx.x;
    if (bx < 6250) {
        const int isbf = wave_isbf(v1w);
        size_t t = (size_t)bx * 256 + threadIdx.x;   // fragment id (16 B)
        if (isbf) {
            fbuf[t] = ((const uint4*)feats)[t];
        } else {
            float4 a = ((const float4*)feats)[2 * t];
            float4 b = ((const float4*)feats)[2 * t + 1];
            union { uint4 q; unsigned short u[8]; } o;
            o.u[0] = f2bf_bits(a.x); o.u[1] = f2bf_bits(a.y);
            o.u[2] = f2bf_bits(a.z); o.u[3] = f2bf_bits(a.w);
            o.u[4] = f2bf_bits(b.x); o.u[5] = f2bf_bits(b.y);
            o.u[6] = f2bf_bits(b.z); o.u[7] = f2bf_bits(b.w);
            fbuf[t] = o.q;
        }
    } else if (bx < 6358) {
        const int isbf = wave_isbf(v1w);
        int t = (bx - 6250) * 256 + threadIdx.x;     // < 27648
        const void* W = (t < 13824) ? W1 : W2;
        uint4* Ws     = (t < 13824) ? Ws1 : Ws2;
        int f = (t < 13824) ? t : t - 13824;
        int k  = f / 512;
        int r  = f % 512;
        int kc = r / 256;
        int r2 = r % 256;
        int nc = r2 / 64;
        int l  = r2 % 64;
        int quad = l >> 4, li = l & 15;
        unsigned short tmp[8];
#pragma unroll
        for (int j = 0; j < 8; ++j) {
            int off = k * 4096 + (kc * 32 + quad * 8 + j) * 64 + (nc * 16 + li);
            tmp[j] = isbf ? ((const unsigned short*)W)[off]
                          : f2bf_bits(((const float*)W)[off]);
        }
        uint4 v;
        v.x = (unsigned)tmp[0] | ((unsigned)tmp[1] << 16);
        v.y = (unsigned)tmp[2] | ((unsigned)tmp[3] << 16);
        v.z = (unsigned)tmp[4] | ((unsigned)tmp[5] << 16);
        v.w = (unsigned)tmp[6] | ((unsigned)tmp[7] << 16);
        Ws[f] = v;
    } else {
        int t = threadIdx.x;
        if (t < 64) {
            int isbf = wave_isbf(v1w);
            int n64ok = 1;
#pragma unroll
            for (int i = 0; i < 8; ++i)   // int64 nbr: every odd dword zero
                if (nbrw[2 * (t * 8 + i) + 1] != 0u) n64ok = 0;
            int n64 = __all(n64ok);
            if (t == 0) { flags[0] = isbf; flags[1] = n64; }
        }
        uint4 z = make_uint4(0u, 0u, 0u, 0u);
        if (t >= 64 && t < 72) fbuf[(size_t)NVOX * 8 + (t - 64)] = z;
        if (t >= 72 && t < 80) hbuf[(size_t)NVOX * 8 + (t - 72)] = z;
    }
}

// async-stage tap kk of ONE 64-row half-tile: this wave's 2 DMA slots cover
// local rows [16w, 16w+16), gated by that group's mask bit (wave-uniform).
// nbr from global (8-lane broadcast, L1-hot); tail rows -> sentinel. Slot s
// holds logical frag f=(s - s/8)&7 of row s/8 (XOR swizzle via address).
#define STG_H(kk, gm, oo0, oo1, bb0, bb1, bp) do {                          \
    if (((gm) >> (kk)) & 1) {                                               \
        int ia_ = (bb0) ? NVOX : nbrG[(oo0) + (kk) * tmul];                 \
        int ib_ = (bb1) ? NVOX : nbrG[(oo1) + (kk) * tmul];                 \
        gload_lds16(srcB + (size_t)ia_ * ROWB + f0 * 16,                    \
                    (void*)((bp) + w * 128));                               \
        gload_lds16(srcB + (size_t)ib_ * ROWB + f1 * 16,                    \
                    (void*)((bp) + w * 128 + 64));                          \
    } } while (0)

#define LOADB(kk, B0r, B1r) do {                                            \
    B0r = Ws[(kk) * 512 + w * 64 + l];                                      \
    B1r = Ws[(kk) * 512 + 256 + w * 64 + l];                                \
} while (0)

// MFMAs of tap kk, half-tile with acc groups [hb, hb+4), group-gated
#define COMPUTE_H(kk, hb, bp, B0, B1) do {                                  \
    _Pragma("unroll")                                                       \
    for (int gl = 0; gl < 4; ++gl) {                                        \
        if ((mg[(hb) + gl] >> (kk)) & 1) {                                  \
            bf16x8 a0_ = *(const bf16x8*)((bp) + ro0[gl]);                  \
            bf16x8 a1_ = *(const bf16x8*)((bp) + ro1[gl]);                  \
            acc[(hb) + gl] = __builtin_amdgcn_mfma_f32_16x16x32_bf16(a0_, B0, acc[(hb) + gl], 0, 0, 0); \
            acc[(hb) + gl] = __builtin_amdgcn_mfma_f32_16x16x32_bf16(a1_, B1, acc[(hb) + gl], 0, 0, 0); \
        }                                                                   \
    }                                                                       \
} while (0)

// -------- fused sparse-conv + BN (+ residual) + ReLU
// R10: the only metric tracking the 66us plateau across R0..R9 is vmem
// instrs/voxel (R0 16.6/64vox; R6 40 -> 146us; bigger tiles cut it but
// lost residency). This cuts the largest term — B loads, 8/block-tap — in
// HALF while keeping R0's exact 64-row round geometry and 17.4KB LDS:
// VPB=128 as TWO half-tiles sharing one register-resident B per tap.
// 54 half-tap rounds (R0 cadence), LOADB once per tap. 12.6 instr/64vox.
__global__ __launch_bounds__(256, 6)
void conv_bn_kernel(const uint4* __restrict__ srcV,   // (NVOX+1) x 8 uint4 bf16 rows
                    const void* __restrict__ nbr,
                    const bf16x8* __restrict__ Ws,
                    const void* __restrict__ gg, const void* __restrict__ bb,
                    const void* __restrict__ mm, const void* __restrict__ vv,
                    const u16x8* __restrict__ resid,  // bf16 fbuf rows, null for conv1
                    const int* __restrict__ flags,
                    void* __restrict__ dst, int final_out) {
    // smi: mask[8] | A-tiles 2x512 uint4 (64 rows each!) at int-ofs 8
    // (byte 32, 16B-aligned, ends int 4104). Epilogue outLDS 64x68 = 4352
    // ints aliases everything (two passes). LDS = 17,408 B.
    __shared__ __align__(16) int smi[64 * OSTR];
    int*   maskLDS = smi;
    uint4* at0     = (uint4*)(smi + 8);
    uint4* at1     = at0 + 512;
    float* outLDS  = (float*)smi;

    const int tid  = threadIdx.x;
    // bijective XCD-aware swizzle (verified: FETCH 46->26-40 MB)
    const int nwg  = gridDim.x;
    const int orig = blockIdx.x;
    const int qq   = nwg >> 3, rr = nwg & 7;
    const int xcd  = orig & 7, idx = orig >> 3;
    const int bid  = (xcd < rr ? xcd * (qq + 1) : rr * (qq + 1) + (xcd - rr) * qq) + idx;
    const int base = bid * VPB;

    const int isbf = flags[0];
    const int n64  = flags[1];
    const char* srcB = (const char*)srcV;

    // nbr as int32 view: element (v*27+k) lives at int32 slot v*smul+k*tmul
    const int* nbrG = (const int*)nbr;
    const int  tmul = n64 ? 2 : 1;
    const int  smul = NTAP * tmul;

    if (tid < 8) maskLDS[tid] = 0;
    __syncthreads();

    // per-(tap, 16-voxel-group) validity bitmask — 8 groups, tail-safe
    if (tid < NTAP * 8) {
        int k = tid >> 3, g = tid & 7;
        int mn = 0x7fffffff;
#pragma unroll
        for (int r = 0; r < 16; ++r) {
            int vx = base + g * 16 + r;
            int safe = vx < NVOX ? vx : NVOX - 1;
            int v = nbrG[safe * smul + k * tmul];
            if (vx >= NVOX) v = NVOX;
            mn = min(mn, v);
        }
        if (mn < NVOX) atomicOr(&maskLDS[g], 1 << k);
    }
    __syncthreads();

    const int w = tid >> 6, l = tid & 63;
    const int quad = l >> 4, li = l & 15;

    int mg[8];
#pragma unroll
    for (int g = 0; g < 8; ++g) mg[g] = __builtin_amdgcn_readfirstlane(maskLDS[g]);
    const int gA = mg[w];       // staging gate, half 0 (group w)
    const int gB = mg[4 + w];   // staging gate, half 1 (group 4+w)

    // staging geometry (identical both halves): wave w's 2 slots cover
    // local rows [16w, 16w+16); global row = base + 64*h + r
    const int s0 = w * 128 + l;
    const int s1 = s0 + 64;
    const int r0 = s0 >> 3, f0 = (s0 - r0) & 7;
    const int r1 = s1 >> 3, f1 = (s1 - r1) & 7;
    int oA0, oA1, oB0, oB1, bA0, bA1, bB0, bB1;
    {
        int vA0 = base + r0,      vA1 = base + r1;
        int vB0 = base + 64 + r0, vB1 = base + 64 + r1;
        bA0 = vA0 >= NVOX; bA1 = vA1 >= NVOX;
        bB0 = vB0 >= NVOX; bB1 = vB1 >= NVOX;
        oA0 = (bA0 ? NVOX - 1 : vA0) * smul;
        oA1 = (bA1 ? NVOX - 1 : vA1) * smul;
        oB0 = (bB0 ? NVOX - 1 : vB0) * smul;
        oB1 = (bB1 ? NVOX - 1 : vB1) * smul;
    }
    // compute-side fragment read offsets (uint4 units, local rows, both halves)
    int ro0[4], ro1[4];
#pragma unroll
    for (int gl = 0; gl < 4; ++gl) {
        int row = gl * 16 + li;
        ro0[gl] = row * 8 + ((quad + row) & 7);
        ro1[gl] = row * 8 + ((quad + 4 + row) & 7);
    }

    f32x4 acc[8];
#pragma unroll
    for (int g = 0; g < 8; ++g) acc[g] = (f32x4){0.f, 0.f, 0.f, 0.f};

    bf16x8 xB0, xB1;

    // prologue: tap 0 half 0 -> at0; B(0) once for both halves
    STG_H(0, gA, oA0, oA1, bA0, bA1, at0);
    LOADB(0, xB0, xB1);
    __syncthreads();   // drains DMA -> at0 (tap 0, half 0) ready

    // 54 half-tap rounds, R0 cadence; one B load per TAP (after last use)
    for (int k = 0; k < 26; ++k) {
        STG_H(k, gB, oB0, oB1, bB0, bB1, at1);       // tap k, half 1
        COMPUTE_H(k, 0, at0, xB0, xB1);              // tap k, half 0
        __syncthreads();   // drains -> at1 ready
        STG_H(k + 1, gA, oA0, oA1, bA0, bA1, at0);   // tap k+1, half 0
        COMPUTE_H(k, 4, at1, xB0, xB1);              // tap k, half 1 (last B(k) use)
        LOADB(k + 1, xB0, xB1);                      // B(k+1), after last use
        __syncthreads();   // drains -> at0 ready
    }
    STG_H(26, gB, oB0, oB1, bB0, bB1, at1);
    COMPUTE_H(26, 0, at0, xB0, xB1);
    __syncthreads();
    COMPUTE_H(26, 4, at1, xB0, xB1);

    // BN + residual + ReLU + store: two 64-row passes through one outLDS
    const int c = w * 16 + li;
    float scale = ld_param(gg, c, isbf) * rsqrtf(ld_param(vv, c, isbf) + 1e-5f);
    float offs  = ld_param(bb, c, isbf) - ld_param(mm, c, isbf) * scale;

#pragma unroll
    for (int h = 0; h < 2; ++h) {
        __syncthreads();   // pass h: tiles/masks (h=0) or prev stores (h=1) done
#pragma unroll
        for (int gl = 0; gl < 4; ++gl)
#pragma unroll
            for (int r = 0; r < 4; ++r)
                outLDS[(gl * 16 + quad * 4 + r) * OSTR + c] = acc[4 * h + gl][r] * scale + offs;
        __syncthreads();

        int trow = tid >> 2, cc = tid & 3;
        long grow = base + 64 * h + trow;
        if (grow < NVOX) {
            const float4* lp = (const float4*)&outLDS[trow * OSTR + cc * 16];
            float4 q0 = lp[0], q1 = lp[1], q2 = lp[2], q3 = lp[3];
            float vals[16] = {q0.x, q0.y, q0.z, q0.w, q1.x, q1.y, q1.z, q1.w,
                              q2.x, q2.y, q2.z, q2.w, q3.x, q3.y, q3.z, q3.w};

            if (resid) {
                const u16x8* rp = resid + grow * 8 + cc * 2;
                u16x8 r0v = rp[0], r1v = rp[1];
#pragma unroll
                for (int j = 0; j < 8; ++j) { vals[j] += bf2f(r0v[j]); vals[8 + j] += bf2f(r1v[j]); }
            }
#pragma unroll
            for (int j = 0; j < 16; ++j) vals[j] = fmaxf(vals[j], 0.f);

            const int store_bf = (!final_out) || isbf;
            if (store_bf) {
                u16x8 o0v, o1v;
#pragma unroll
                for (int j = 0; j < 8; ++j) { o0v[j] = f2bf_bits(vals[j]); o1v[j] = f2bf_bits(vals[8 + j]); }
                u16x8* dp = (u16x8*)dst + grow * 8 + cc * 2;
                dp[0] = o0v; dp[1] = o1v;
            } else {
                float4* dp = (float4*)dst + grow * 16 + cc * 4;
                dp[0] = (float4){vals[0], vals[1], vals[2], vals[3]};
                dp[1] = (float4){vals[4], vals[5], vals[6], vals[7]};
                dp[2] = (float4){vals[8], vals[9], vals[10], vals[11]};
                dp[3] = (float4){vals[12], vals[13], vals[14], vals[15]};
            }
        }
    }
}

extern "C" void kernel_launch(void* const* d_in, const int* in_sizes, int n_in,
                              void* d_out, int out_size, void* d_ws, size_t ws_size,
                              hipStream_t stream) {
    const void* feats = d_in[0];
    const void* nbr   = d_in[1];
    const void* W1    = d_in[2];
    const void* g1    = d_in[3];
    const void* b1    = d_in[4];
    const void* m1    = d_in[5];
    const void* v1    = d_in[6];
    const void* W2    = d_in[7];
    const void* g2    = d_in[8];
    const void* b2    = d_in[9];
    const void* m2    = d_in[10];
    const void* v2    = d_in[11];

    char* ws = (char*)d_ws;
    uint4* fbuf = (uint4*)(ws + FB_OFF);
    uint4* hbuf = (uint4*)(ws + H_OFF);
    uint4* Ws1  = (uint4*)(ws + WS1_OFF);
    uint4* Ws2  = (uint4*)(ws + WS2_OFF);
    int*   flags = (int*)(ws + FLAG_OFF);

    prep_kernel<<<dim3(6359), dim3(256), 0, stream>>>(
        feats, W1, W2, (const unsigned*)v1, (const unsigned*)nbr,
        fbuf, hbuf, Ws1, Ws2, flags);

    const int nblk = (NVOX + VPB - 1) / VPB;   // 1563 (tail clamped)
    conv_bn_kernel<<<dim3(nblk), dim3(256), 0, stream>>>(
        fbuf, nbr, (const bf16x8*)Ws1, g1, b1, m1, v1,
        /*resid=*/nullptr, flags, hbuf, /*final_out=*/0);

    conv_bn_kernel<<<dim3(nblk), dim3(256), 0, stream>>>(
        hbuf, nbr, (const bf16x8*)Ws2, g2, b2, m2, v2,
        /*resid=*/(const u16x8*)fbuf, flags, d_out, /*final_out=*/1);
}